// Round 5
// baseline (339.365 us; speedup 1.0000x reference)
//
#include <hip/hip_runtime.h>
#include <hip/hip_bf16.h>
#include <stdint.h>

#define EPS 1e-10f
#define BLOCK 256
#define GRID1 2048
#define WPB 4                  // waves per block
#define STEP_BYTES 1024        // per stream per wave-step (64 lanes x 16 B)
#define LN2F 0.69314718055994530942f

// R4 post-mortem: compiler sank the "register array" loads (VGPR stayed 32);
// and corrected Little's-law math shows MLP was never the limiter anyway --
// four VGPR-return structures all pinned at ~1.35 TB/s. R5 is the decisive
// structural experiment: global_load_lds DMA staging (m97-proven path), wave-
// private LDS double buffer, explicit vmcnt waits, zero barriers in the loop.

__device__ __forceinline__ void glds16(const void* g, void* l) {
  __builtin_amdgcn_global_load_lds(
      (const __attribute__((address_space(1))) unsigned int*)g,
      (__attribute__((address_space(3))) unsigned int*)l, 16, 0, 0);
}

__global__ __launch_bounds__(BLOCK) void sparse_loss_stage1(
    const float* __restrict__ pred,
    const int* __restrict__ y,
    const int* __restrict__ lamda_p,
    float* __restrict__ partials,   // [GRID1]
    long long nvec,                 // number of float4 groups
    long long total) {              // total element count
  // per-wave-private double buffers: [wave][buf][pred 1KB | y 1KB]
  __shared__ __align__(16) unsigned char lds[WPB][2][2 * STEP_BYTES];
  __shared__ float ssum[WPB];

  const int tid = threadIdx.x;
  const int wave = tid >> 6;
  const int lane = tid & 63;
  const float lam = (float)(*lamda_p);
  float acc = 0.0f;  // accumulates +c*log2(a); sign & ln2 applied in stage 2

#define ELEM(P, Y)                                              \
  {                                                             \
    const bool z = ((Y) == 0);                                  \
    const float a = EPS + (z ? (1.0f - (P)) : (P));             \
    acc = fmaf(z ? 1.0f : lam, __log2f(a), acc);                \
  }

  // ---- main streaming: contiguous per-wave step ranges, balanced +-1 ----
  const long long nsteps = nvec >> 6;  // full 64-group (1 KB/stream) steps
  const long long wid = (long long)blockIdx.x * WPB + wave;
  const long long nw = (long long)gridDim.x * WPB;
  const long long s0 = (wid * nsteps) / nw;
  const long long s1 = ((wid + 1) * nsteps) / nw;

  const char* pb = (const char*)pred;
  const char* yb = (const char*)y;
  char* const lp0 = (char*)&lds[wave][0][0];
  char* const lp1 = (char*)&lds[wave][1][0];

  // stage step s into buffer b: 2 fire-and-forget DMA loads, no VGPR dest.
  // lgkmcnt(0) first = WAR guard (prior ds_reads of this buffer drained).
#define STAGE(S, LB)                                                       \
  {                                                                        \
    asm volatile("s_waitcnt lgkmcnt(0)" ::: "memory");                     \
    const long long off_ = (S) * (long long)STEP_BYTES + lane * 16;        \
    glds16(pb + off_, (LB));                                               \
    glds16(yb + off_, (LB) + STEP_BYTES);                                  \
  }

  if (s0 < s1) STAGE(s0, lp0);
  for (long long s = s0; s < s1; ++s) {
    char* const lb = ((s - s0) & 1) ? lp1 : lp0;
    if (s + 1 < s1) {
      char* const nb = ((s - s0) & 1) ? lp0 : lp1;
      STAGE(s + 1, nb);
      asm volatile("s_waitcnt vmcnt(2)" ::: "memory");  // step s's 2 DMAs done
    } else {
      asm volatile("s_waitcnt vmcnt(0)" ::: "memory");
    }
    const float4 p = *(const float4*)(lb + lane * 16);
    const int4 yy = *(const int4*)(lb + STEP_BYTES + lane * 16);
    ELEM(p.x, yy.x)
    ELEM(p.y, yy.y)
    ELEM(p.z, yy.z)
    ELEM(p.w, yy.w)
  }
#undef STAGE

  // ---- generic tails (empty for this problem size, kept for safety) ----
  const long long gtid = (long long)blockIdx.x * BLOCK + tid;
  const long long gstride = (long long)gridDim.x * BLOCK;
  for (long long j = (nsteps << 6) + gtid; j < nvec; j += gstride) {
    const float4 p = reinterpret_cast<const float4*>(pred)[j];
    const int4 yy = reinterpret_cast<const int4*>(y)[j];
    ELEM(p.x, yy.x)
    ELEM(p.y, yy.y)
    ELEM(p.z, yy.z)
    ELEM(p.w, yy.w)
  }
  for (long long j = (nvec << 2) + gtid; j < total; j += gstride) {
    const float p = pred[j];
    ELEM(p, y[j])
  }
#undef ELEM

  // ---- wave64 butterfly reduce, then cross-wave via LDS ----
  for (int off = 32; off > 0; off >>= 1)
    acc += __shfl_down(acc, off, 64);

  if (lane == 0) ssum[wave] = acc;
  __syncthreads();

  if (tid == 0)
    partials[blockIdx.x] = ssum[0] + ssum[1] + ssum[2] + ssum[3];
}

__global__ __launch_bounds__(BLOCK) void sparse_loss_stage2(
    const float* __restrict__ partials,  // [GRID1]
    float* __restrict__ out,
    float inv_total) {
  float acc = 0.0f;
  for (int i = threadIdx.x; i < GRID1; i += BLOCK)
    acc += partials[i];

  for (int off = 32; off > 0; off >>= 1)
    acc += __shfl_down(acc, off, 64);

  __shared__ float ssum[4];
  const int lane = threadIdx.x & 63;
  const int wave = threadIdx.x >> 6;
  if (lane == 0) ssum[wave] = acc;
  __syncthreads();

  if (threadIdx.x == 0) {
    // loss = -mean; accumulated log2 -> scale by ln2 here
    out[0] = -(ssum[0] + ssum[1] + ssum[2] + ssum[3]) * inv_total * LN2F;
  }
}

extern "C" void kernel_launch(void* const* d_in, const int* in_sizes, int n_in,
                              void* d_out, int out_size, void* d_ws, size_t ws_size,
                              hipStream_t stream) {
  const float* pred = (const float*)d_in[0];
  const int* y = (const int*)d_in[1];
  const int* lamda = (const int*)d_in[2];
  float* out = (float*)d_out;
  float* partials = (float*)d_ws;  // 2048 floats = 8 KB scratch

  const long long total = (long long)in_sizes[0];
  const long long nvec = total / 4;
  const float inv_total = 1.0f / (float)total;

  sparse_loss_stage1<<<GRID1, BLOCK, 0, stream>>>(pred, y, lamda, partials,
                                                  nvec, total);
  sparse_loss_stage2<<<1, BLOCK, 0, stream>>>(partials, out, inv_total);
}